// Round 11
// baseline (620.858 us; speedup 1.0000x reference)
//
#include <hip/hip_runtime.h>
#include <cstddef>
#include <cstdint>

// Problem constants (from reference)
#define NN 100000
#define NE 1600000
// F_IN=16, HID=128, OUT=4, K=3

// Coarse bucketing for CSR build: 64 nodes per bucket
#define CB 1563              // ceil(NN/64)
#define CBP 1568             // padded bucket count (multiple of 32)
#define EPB 4096             // edges per block in pass A
#define A1B 391              // ceil(NE/EPB)

typedef unsigned short u16;
using short8 = __attribute__((ext_vector_type(8))) short;  // 8 bf16 (4 VGPRs)
using f32x4  = __attribute__((ext_vector_type(4))) float;  // MFMA accum

// bf16 helpers (round-to-nearest-even via bit trick)
__device__ inline u16 f2bf(float f) {
    unsigned u = __float_as_uint(f);
    unsigned r = u + 0x7fffu + ((u >> 16) & 1u);
    return (u16)(r >> 16);
}
__device__ inline float bflo(unsigned u) { return __uint_as_float(u << 16); }
__device__ inline float bfhi(unsigned u) { return __uint_as_float(u & 0xffff0000u); }

// 4-byte edge record: [31:17] = bf16 weight sans sign (w >= 0), [16:0] = src
__device__ inline float ew_of(unsigned p) { return __uint_as_float((p >> 17) << 16); }
__device__ inline int   src_of(unsigned p) { return (int)(p & 0x1FFFFu); }

// ---------------------------------------------------------------------------
// Graph preprocessing: atomic-free two-level bucket CSR build.
// ---------------------------------------------------------------------------

// A1: per-block histogram of coarse buckets -> M[blk][CBP]
__global__ __launch_bounds__(256) void hist_k(const int* __restrict__ col,
                                              unsigned* __restrict__ M) {
    __shared__ unsigned h[CBP];
    for (int i = threadIdx.x; i < CBP; i += 256) h[i] = 0;
    __syncthreads();
    int base = blockIdx.x * EPB;
    for (int i = threadIdx.x; i < EPB; i += 256) {
        int e = base + i;
        if (e < NE) atomicAdd(&h[col[e] >> 6], 1u);
    }
    __syncthreads();
    unsigned* mrow = M + (size_t)blockIdx.x * CBP;
    for (int i = threadIdx.x; i < CBP; i += 256) mrow[i] = h[i];
}

// A2a: column totals of M -> tot[CBP]
__global__ __launch_bounds__(256) void totals_k(const unsigned* __restrict__ M,
                                                unsigned* __restrict__ tot) {
    int b = blockIdx.x * 256 + threadIdx.x;
    if (b >= CBP) return;
    unsigned s = 0;
    for (int r = 0; r < A1B; ++r) s += M[(size_t)r * CBP + b];
    tot[b] = s;
}

// A2b: exclusive scan of tot -> cb[0..CBP]  (single block)
__global__ __launch_bounds__(256) void scanb_k(const unsigned* __restrict__ tot,
                                               unsigned* __restrict__ cb) {
    __shared__ unsigned part[256];
    int t = threadIdx.x;
    unsigned loc[7];
    unsigned s = 0;
#pragma unroll
    for (int k = 0; k < 7; ++k) {
        int i = t * 7 + k;
        unsigned v = (i < CBP) ? tot[i] : 0;
        loc[k] = s; s += v;
    }
    part[t] = s;
    __syncthreads();
    for (int off = 1; off < 256; off <<= 1) {
        unsigned x = (t >= off) ? part[t - off] : 0;
        __syncthreads();
        part[t] += x;
        __syncthreads();
    }
    unsigned base = (t > 0) ? part[t - 1] : 0;
#pragma unroll
    for (int k = 0; k < 7; ++k) {
        int i = t * 7 + k;
        if (i <= CBP) cb[i] = base + loc[k];
    }
}

// A2c: rewrite M in place to per-(blk,bucket) base
__global__ __launch_bounds__(256) void base_k(const unsigned* __restrict__ cb,
                                              unsigned* __restrict__ M) {
    int b = blockIdx.x * 256 + threadIdx.x;
    if (b >= CBP) return;
    unsigned run = cb[b];
    for (int r = 0; r < A1B; ++r) {
        unsigned v = M[(size_t)r * CBP + b];
        M[(size_t)r * CBP + b] = run;
        run += v;
    }
}

// A3: partition edges into bucket segments (packed: src | colLow<<17, w)
__global__ __launch_bounds__(256) void part_k(const int* __restrict__ row,
                                              const int* __restrict__ col,
                                              const float* __restrict__ ew,
                                              const unsigned* __restrict__ M,
                                              int2* __restrict__ Abuf) {
    __shared__ unsigned cur[CBP];
    const unsigned* mrow = M + (size_t)blockIdx.x * CBP;
    for (int i = threadIdx.x; i < CBP; i += 256) cur[i] = mrow[i];
    __syncthreads();
    int base = blockIdx.x * EPB;
    for (int i = threadIdx.x; i < EPB; i += 256) {
        int e = base + i;
        if (e < NE) {
            int c = col[e];
            unsigned pos = atomicAdd(&cur[c >> 6], 1u);
            Abuf[pos] = make_int2(row[e] | ((c & 63) << 17), __float_as_int(ew[e]));
        }
    }
}

// B: per-bucket LDS counting sort -> epair + rowptr; fused deg/dis.
__global__ __launch_bounds__(256) void build_k(const int2* __restrict__ Abuf,
                                               const unsigned* __restrict__ cb,
                                               int* __restrict__ rowptr,
                                               int2* __restrict__ epair,
                                               float* __restrict__ dis) {
    int b = blockIdx.x;     // 0..CB-1
    int t = threadIdx.x;
    __shared__ int cnt[64];
    __shared__ int offs[64];
    __shared__ int ex[64];
    __shared__ float dsum[64];
    if (t < 64) { cnt[t] = 0; dsum[t] = 0.f; }
    __syncthreads();
    unsigned s = cb[b], e = cb[b + 1];
    int n = (int)(e - s);
    // pass 1: count + weighted degree
    for (int i = t; i < n; i += 256) {
        int2 p = Abuf[s + i];
        int cl = (p.x >> 17) & 63;
        atomicAdd(&cnt[cl], 1);
        atomicAdd(&dsum[cl], __int_as_float(p.y));
    }
    __syncthreads();
    // exclusive scan of cnt[64]
    if (t < 64) offs[t] = cnt[t];
    __syncthreads();
    for (int off = 1; off < 64; off <<= 1) {
        int x = 0;
        if (t < 64 && t >= off) x = offs[t - off];
        __syncthreads();
        if (t < 64) offs[t] += x;
        __syncthreads();
    }
    if (t < 64) { ex[t] = offs[t] - cnt[t]; cnt[t] = 0; }
    __syncthreads();
    // pass 2: scatter into sorted positions (2nd read hits L2)
    for (int i = t; i < n; i += 256) {
        int2 p = Abuf[s + i];
        int cl = (p.x >> 17) & 63;
        int r = atomicAdd(&cnt[cl], 1);
        epair[s + ex[cl] + r] = make_int2(p.x & 0x1FFFF, p.y);
    }
    // rowptr + dis
    if (t < 64) {
        int v = b * 64 + t;
        if (v < NN) {
            rowptr[v] = (int)s + ex[t];
            float d = dsum[t];
            dis[v] = (d > 0.f) ? (1.0f / sqrtf(d)) : 0.f;
        }
    }
    if (b == CB - 1 && t == 0) rowptr[NN] = NE;
}

// norm + compress: epc[i] = (bf16bits(dis[src]*w*dis[v]) & 0x7FFF)<<17 | src
__global__ void norm_k(const int* __restrict__ rowptr, const float* __restrict__ dis,
                       const int2* __restrict__ epair, unsigned* __restrict__ epc) {
    int v = blockIdx.x * 256 + threadIdx.x;
    if (v >= NN) return;
    float dv = dis[v];
    int s = rowptr[v], e = rowptr[v + 1];
    for (int i = s; i < e; ++i) {
        int2 p = epair[i];
        float w = dis[p.x] * __int_as_float(p.y) * dv;
        unsigned wb = (unsigned)f2bf(w) & 0x7FFFu;
        epc[i] = (wb << 17) | (unsigned)p.x;
    }
}

// ---------------------------------------------------------------------------
// Weight prep: Wt[j][k] = bf16(W[k][j]);  W is [K][128] fp32, Wt is [128][K]
// ---------------------------------------------------------------------------
template <int K>
__global__ void wt_k(const float* __restrict__ W, u16* __restrict__ Wt) {
    int id = blockIdx.x * 256 + threadIdx.x;   // grid = 128*K/256
    int j = id / K, k = id % K;
    Wt[(size_t)j * K + k] = f2bf(W[(size_t)k * 128 + j]);
}

// ---------------------------------------------------------------------------
// Layer-0 feature pipeline (bf16 16-wide in Xcat [NN][64], slices of 16)
// ---------------------------------------------------------------------------

// x fp32 [NN][16] -> Xcat slice0 bf16
__global__ void cvt16_k(const float* __restrict__ x, u16* __restrict__ Xcat) {
    int t = blockIdx.x * 256 + threadIdx.x;   // NN*2 threads
    if (t >= NN * 2) return;
    int v = t >> 1, hf = t & 1;
    const float* src = x + (size_t)v * 16 + hf * 8;
    unsigned* dst = (unsigned*)(Xcat + (size_t)v * 64 + hf * 8);
#pragma unroll
    for (int f = 0; f < 4; ++f)
        dst[f] = (unsigned)f2bf(src[2 * f]) | ((unsigned)f2bf(src[2 * f + 1]) << 16);
}

// 16-wide bf16 prop in stride-64 concat: ONE wave per node; 8 lanes serve one
// edge (uint = 2 features each) -> 8 edges per wave-load, unroll x2.
__global__ __launch_bounds__(256) void prop16b_k(
    const u16* __restrict__ hin, u16* __restrict__ hout,
    const int* __restrict__ rowptr, const unsigned* __restrict__ epc) {
    int wid = (blockIdx.x * 256 + threadIdx.x) >> 6;   // grid = NN*64/256
    int lane = threadIdx.x & 63;
    int g = lane >> 3;          // edge group 0..7
    int l = lane & 7;           // feature pair: features [2l, 2l+1]
    int v = __builtin_amdgcn_readfirstlane(wid);
    int s = rowptr[v], e = rowptr[v + 1];
    const u16* __restrict__ hb = hin + l * 2;
    float a0 = 0.f, a1 = 0.f, b0 = 0.f, b1 = 0.f;
    int i = s;
    for (; i + 15 < e; i += 16) {
        unsigned pa = epc[i + g];
        unsigned pb = epc[i + 8 + g];
        unsigned ua = *(const unsigned*)(hb + (size_t)src_of(pa) * 64);
        unsigned ub = *(const unsigned*)(hb + (size_t)src_of(pb) * 64);
        float wa = ew_of(pa), wb = ew_of(pb);
        a0 += wa * bflo(ua); a1 += wa * bfhi(ua);
        b0 += wb * bflo(ub); b1 += wb * bfhi(ub);
    }
    for (; i < e; i += 8) {
        int idx = i + g;
        unsigned p = (idx < e) ? epc[idx] : 0u;
        unsigned u = *(const unsigned*)(hb + (size_t)src_of(p) * 64);
        float w = ew_of(p);
        a0 += w * bflo(u); a1 += w * bfhi(u);
    }
    a0 += b0; a1 += b1;
#pragma unroll
    for (int m = 8; m <= 32; m <<= 1) {
        a0 += __shfl_xor(a0, m);
        a1 += __shfl_xor(a1, m);
    }
    if (g == 0) {
        *(unsigned*)(hout + (size_t)v * 64 + l * 2) =
            (unsigned)f2bf(a0) | ((unsigned)f2bf(a1) << 16);
    }
}

// 128-wide bf16 prop: ONE wave per node; 16 lanes serve one edge with
// dwordx4 (16B = 8 features per lane) -> 4 edges per wave-load, unroll x2.
// At the L2-miss service ceiling for this random-gather pattern (R5/R6/R7).
__global__ __launch_bounds__(256) void propbf_k(
    const u16* __restrict__ hin, u16* __restrict__ hout,
    const int* __restrict__ rowptr, const unsigned* __restrict__ epc) {
    int wid = (blockIdx.x * 256 + threadIdx.x) >> 6;   // grid = NN*64/256
    int lane = threadIdx.x & 63;
    int g = lane >> 4;          // edge group 0..3
    int l = lane & 15;          // feature slot: features [8l, 8l+8)
    int v = __builtin_amdgcn_readfirstlane(wid);
    int s = rowptr[v], e = rowptr[v + 1];
    const u16* __restrict__ hb = hin + l * 8;
    float a[8];
#pragma unroll
    for (int k = 0; k < 8; ++k) a[k] = 0.f;

    int i = s;
    for (; i + 7 < e; i += 8) {
        unsigned pa = epc[i + g];
        unsigned pb = epc[i + 4 + g];
        uint4 ha = *(const uint4*)(hb + (size_t)src_of(pa) * 512);
        uint4 hc = *(const uint4*)(hb + (size_t)src_of(pb) * 512);
        float wa = ew_of(pa), wb = ew_of(pb);
        a[0] += wa * bflo(ha.x); a[1] += wa * bfhi(ha.x);
        a[2] += wa * bflo(ha.y); a[3] += wa * bfhi(ha.y);
        a[4] += wa * bflo(ha.z); a[5] += wa * bfhi(ha.z);
        a[6] += wa * bflo(ha.w); a[7] += wa * bfhi(ha.w);
        a[0] += wb * bflo(hc.x); a[1] += wb * bfhi(hc.x);
        a[2] += wb * bflo(hc.y); a[3] += wb * bfhi(hc.y);
        a[4] += wb * bflo(hc.z); a[5] += wb * bfhi(hc.z);
        a[6] += wb * bflo(hc.w); a[7] += wb * bfhi(hc.w);
    }
    for (; i < e; i += 4) {
        int idx = i + g;
        unsigned p = (idx < e) ? epc[idx] : 0u;
        uint4 h = *(const uint4*)(hb + (size_t)src_of(p) * 512);
        float w = ew_of(p);
        a[0] += w * bflo(h.x); a[1] += w * bfhi(h.x);
        a[2] += w * bflo(h.y); a[3] += w * bfhi(h.y);
        a[4] += w * bflo(h.z); a[5] += w * bfhi(h.z);
        a[6] += w * bflo(h.w); a[7] += w * bfhi(h.w);
    }
#pragma unroll
    for (int k = 0; k < 8; ++k) {
        a[k] += __shfl_xor(a[k], 16);
        a[k] += __shfl_xor(a[k], 32);
    }
    if (g == 0) {
        uint4 o;
        o.x = (unsigned)f2bf(a[0]) | ((unsigned)f2bf(a[1]) << 16);
        o.y = (unsigned)f2bf(a[2]) | ((unsigned)f2bf(a[3]) << 16);
        o.z = (unsigned)f2bf(a[4]) | ((unsigned)f2bf(a[5]) << 16);
        o.w = (unsigned)f2bf(a[6]) | ((unsigned)f2bf(a[7]) << 16);
        *(uint4*)(hout + (size_t)v * 512 + l * 8) = o;
    }
}

// ---------------------------------------------------------------------------
// MFMA GEMM v4: C[NN][128] = A[NN][K]bf16 @ W[K][128] (+bias, relu) -> bf16
// (out stride 512), or with FC=1 fused 128->4 projection -> fp32 out [NN][4].
// B staged in 16KB K-chunks, double-buffered (32KB LDS). One 256-row tile
// per block (grid=391): write locality (R8) + occupancy (R9 lessons).
// ---------------------------------------------------------------------------
template <int K, int RELU, int FC>
__global__ __launch_bounds__(512) void mgemm3_k(
    const u16* __restrict__ A, const u16* __restrict__ Bt,
    const float* __restrict__ bias, u16* __restrict__ outb,
    const float* __restrict__ Wfc, const float* __restrict__ bfc,
    float* __restrict__ outf) {
    const int NCH = K / 64;               // 16KB chunks
    __shared__ u16 smB[2][64 * 128];
    int tid = threadIdx.x;
    int lane = tid & 63;
    int wv = tid >> 6;
    int r = lane & 15, h = lane >> 4;

    int v0 = blockIdx.x * 256 + wv * 32;
    bool active = v0 < NN;
    int arow0 = active ? v0 : 0;
    const u16* a0p = A + (size_t)(arow0 + r) * K + h * 8;
    const u16* a1p = a0p + (size_t)16 * K;

    float bj[8];
#pragma unroll
    for (int j = 0; j < 8; ++j) bj[j] = bias[j * 16 + r];

    // staging addresses (chunk image byte d; LDS[d] = IMG[d ^ swz(row)])
    int da = wv * 1024 + lane * 16;
    int db = da + 8192;
    int rowa = da >> 7, rowb = db >> 7;
    int sa = (da ^ ((rowa & 7) << 4)) & 127;
    int sb = (db ^ ((rowb & 7) << 4)) & 127;
    const char* gA = (const char*)Bt + (size_t)rowa * (2 * K) + sa;
    const char* gB = (const char*)Bt + (size_t)rowb * (2 * K) + sb;

    // prologue: stage chunk 0 into buf 0
    short8 ga = *(const short8*)(gA);
    short8 gb = *(const short8*)(gB);
    *(short8*)((char*)smB[0] + da) = ga;
    *(short8*)((char*)smB[0] + db) = gb;
    __syncthreads();

    f32x4 acc0[8], acc1[8];
#pragma unroll
    for (int j = 0; j < 8; ++j) {
        acc0[j] = {0.f, 0.f, 0.f, 0.f};
        acc1[j] = {0.f, 0.f, 0.f, 0.f};
    }

    int buf = 0;
    for (int c = 0; c < NCH; ++c) {
        // issue loads for next chunk (hide under compute)
        if (c + 1 < NCH) {
            ga = *(const short8*)(gA + (c + 1) * 128);
            gb = *(const short8*)(gB + (c + 1) * 128);
        }
        const char* bbase = (const char*)smB[buf];
#pragma unroll
        for (int kk = 0; kk < 2; ++kk) {
            short8 a0 = *(const short8*)(a0p + c * 64 + kk * 32);
            short8 a1 = *(const short8*)(a1p + c * 64 + kk * 32);
#pragma unroll
            for (int j = 0; j < 8; ++j) {
                int bb = ((j * 16 + r) * 128 + kk * 64 + h * 16) ^ ((r & 7) << 4);
                short8 b = *(const short8*)(bbase + bb);
                acc0[j] = __builtin_amdgcn_mfma_f32_16x16x32_bf16(a0, b, acc0[j], 0, 0, 0);
                acc1[j] = __builtin_amdgcn_mfma_f32_16x16x32_bf16(a1, b, acc1[j], 0, 0, 0);
            }
        }
        if (c + 1 < NCH) {
            *(short8*)((char*)smB[buf ^ 1] + da) = ga;
            *(short8*)((char*)smB[buf ^ 1] + db) = gb;
        }
        __syncthreads();
        buf ^= 1;
    }

    if (!active) return;

    if (!FC) {
        // Epilogue: i-outer, j-inner so 32B half-line stores are adjacent.
#pragma unroll
        for (int i = 0; i < 4; ++i) {
            int row0 = v0 + h * 4 + i;
#pragma unroll
            for (int j = 0; j < 8; ++j) {
                float c0 = acc0[j][i] + bj[j];
                float c1 = acc1[j][i] + bj[j];
                if (RELU) { c0 = fmaxf(c0, 0.f); c1 = fmaxf(c1, 0.f); }
                outb[(size_t)row0 * 512 + j * 16 + r] = f2bf(c0);
                outb[(size_t)(row0 + 16) * 512 + j * 16 + r] = f2bf(c1);
            }
        }
    } else {
        // Fused 128->4 projection: wave holds full rows; reduce over cols.
        float4 wf[8];
#pragma unroll
        for (int j = 0; j < 8; ++j)
            wf[j] = reinterpret_cast<const float4*>(Wfc)[j * 16 + r];
        float p0[4][4], p1[4][4];
#pragma unroll
        for (int i = 0; i < 4; ++i)
#pragma unroll
            for (int o = 0; o < 4; ++o) { p0[i][o] = 0.f; p1[i][o] = 0.f; }
#pragma unroll
        for (int j = 0; j < 8; ++j) {
#pragma unroll
            for (int i = 0; i < 4; ++i) {
                float c0 = acc0[j][i] + bj[j];
                float c1 = acc1[j][i] + bj[j];
                p0[i][0] += c0 * wf[j].x; p0[i][1] += c0 * wf[j].y;
                p0[i][2] += c0 * wf[j].z; p0[i][3] += c0 * wf[j].w;
                p1[i][0] += c1 * wf[j].x; p1[i][1] += c1 * wf[j].y;
                p1[i][2] += c1 * wf[j].z; p1[i][3] += c1 * wf[j].w;
            }
        }
        // reduce across the 16 lanes (r) of each h-group
#pragma unroll
        for (int i = 0; i < 4; ++i)
#pragma unroll
            for (int o = 0; o < 4; ++o)
#pragma unroll
                for (int m = 1; m <= 8; m <<= 1) {
                    p0[i][o] += __shfl_xor(p0[i][o], m);
                    p1[i][o] += __shfl_xor(p1[i][o], m);
                }
        if (r == 0) {
            float b0 = bfc[0], b1 = bfc[1], b2 = bfc[2], b3 = bfc[3];
#pragma unroll
            for (int i = 0; i < 4; ++i) {
                int row0 = v0 + h * 4 + i;
                reinterpret_cast<float4*>(outf)[row0] =
                    make_float4(p0[i][0] + b0, p0[i][1] + b1, p0[i][2] + b2, p0[i][3] + b3);
                reinterpret_cast<float4*>(outf)[row0 + 16] =
                    make_float4(p1[i][0] + b0, p1[i][1] + b1, p1[i][2] + b2, p1[i][3] + b3);
            }
        }
    }
}

// ---------------------------------------------------------------------------

extern "C" void kernel_launch(void* const* d_in, const int* in_sizes, int n_in,
                              void* d_out, int out_size, void* d_ws, size_t ws_size,
                              hipStream_t stream) {
    const float* x    = (const float*)d_in[0];
    const int*   ei   = (const int*)d_in[1];      // [2][E] int32
    const float* ea   = (const float*)d_in[2];    // [E]
    const float* W0   = (const float*)d_in[3];    // [4][16][128] = [64][128]
    const float* b0   = (const float*)d_in[4];
    const float* W1   = (const float*)d_in[5];    // [4][128][128] = [512][128]
    const float* b1   = (const float*)d_in[6];
    const float* W2   = (const float*)d_in[7];
    const float* b2   = (const float*)d_in[8];
    const float* Wfc  = (const float*)d_in[9];    // [128][4]
    const float* bfc  = (const float*)d_in[10];
    float* out = (float*)d_out;

    const int* row = ei;
    const int* col = ei + NE;

    // ws layout (256B aligned chunks), ~150 MB total
    char* w = (char*)d_ws;
    size_t off = 0;
    auto alloc = [&](size_t bytes) {
        size_t o = off;
        off += (bytes + 255) & ~(size_t)255;
        return (void*)(w + o);
    };
    int*      rowptr = (int*)     alloc((size_t)(NN + 1) * 4);
    float*    dis    = (float*)   alloc((size_t)NN * 4);
    unsigned* M      = (unsigned*)alloc((size_t)A1B * CBP * 4);  // 2.45 MB
    unsigned* tot    = (unsigned*)alloc((size_t)CBP * 4);
    unsigned* cb     = (unsigned*)alloc((size_t)(CBP + 1) * 4);
    int2*     Abuf   = (int2*)    alloc((size_t)NE * 8);         // 12.8 MB
    int2*     epair  = (int2*)    alloc((size_t)NE * 8);         // 12.8 MB
    unsigned* epc    = (unsigned*)alloc((size_t)NE * 4);         // 6.4 MB
    u16*      Wt0    = (u16*)     alloc((size_t)128 * 64 * 2);
    u16*      Wt1    = (u16*)     alloc((size_t)128 * 512 * 2);
    u16*      Wt2    = (u16*)     alloc((size_t)128 * 512 * 2);
    u16*      Xcat   = (u16*)     alloc((size_t)NN * 64 * 2);    // 12.8 MB
    u16*      Hcat   = (u16*)     alloc((size_t)NN * 512 * 2);   // 102.4 MB
    (void)ws_size;

    const int nScanB = (NN + 255) / 256;  // 391
    const int nPropB = NN * 64 / 256;     // 25000 (one wave per node)
    const int nTiles = (NN + 255) / 256;  // 391 row-tiles of 256
    const int nBkt   = (CBP + 255) / 256; // 7

    // CSR build (atomic-free, streaming; no global memset needed)
    hist_k  <<<A1B,  256, 0, stream>>>(col, M);
    totals_k<<<nBkt, 256, 0, stream>>>(M, tot);
    scanb_k <<<1,    256, 0, stream>>>(tot, cb);
    base_k  <<<nBkt, 256, 0, stream>>>(cb, M);
    part_k  <<<A1B,  256, 0, stream>>>(row, col, ea, M, Abuf);
    build_k <<<CB,   256, 0, stream>>>(Abuf, cb, rowptr, epair, dis);
    norm_k  <<<nScanB, 256, 0, stream>>>(rowptr, dis, epair, epc);

    // Weight transposes (bf16)
    wt_k<64> <<<32,  256, 0, stream>>>(W0, Wt0);
    wt_k<512><<<256, 256, 0, stream>>>(W1, Wt1);
    wt_k<512><<<256, 256, 0, stream>>>(W2, Wt2);

    // Layer 0: bf16 16-wide hops in Xcat slices, MFMA K=64 -> Hcat slice0
    cvt16_k<<<(NN * 2 + 255) / 256, 256, 0, stream>>>(x, Xcat);
    prop16b_k<<<nPropB, 256, 0, stream>>>(Xcat,      Xcat + 16, rowptr, epc);
    prop16b_k<<<nPropB, 256, 0, stream>>>(Xcat + 16, Xcat + 32, rowptr, epc);
    prop16b_k<<<nPropB, 256, 0, stream>>>(Xcat + 32, Xcat + 48, rowptr, epc);
    mgemm3_k<64, 1, 0><<<nTiles, 512, 0, stream>>>(Xcat, Wt0, b0, Hcat,
                                                   nullptr, nullptr, nullptr);

    // Layer 1: hops fill slices 1..3, fused GEMM K=512 -> slice0 (in place)
    propbf_k<<<nPropB, 256, 0, stream>>>(Hcat,       Hcat + 128, rowptr, epc);
    propbf_k<<<nPropB, 256, 0, stream>>>(Hcat + 128, Hcat + 256, rowptr, epc);
    propbf_k<<<nPropB, 256, 0, stream>>>(Hcat + 256, Hcat + 384, rowptr, epc);
    mgemm3_k<512, 1, 0><<<nTiles, 512, 0, stream>>>(Hcat, Wt1, b1, Hcat,
                                                    nullptr, nullptr, nullptr);

    // Layer 2: hops, then final GEMM with fused 128->4 projection -> out
    propbf_k<<<nPropB, 256, 0, stream>>>(Hcat,       Hcat + 128, rowptr, epc);
    propbf_k<<<nPropB, 256, 0, stream>>>(Hcat + 128, Hcat + 256, rowptr, epc);
    propbf_k<<<nPropB, 256, 0, stream>>>(Hcat + 256, Hcat + 384, rowptr, epc);
    mgemm3_k<512, 0, 1><<<nTiles, 512, 0, stream>>>(Hcat, Wt2, b2, nullptr,
                                                    Wfc, bfc, out);
}

// Round 12
// 607.298 us; speedup vs baseline: 1.0223x; 1.0223x over previous
//
#include <hip/hip_runtime.h>
#include <cstddef>
#include <cstdint>

// Problem constants (from reference)
#define NN 100000
#define NE 1600000
// F_IN=16, HID=128, OUT=4, K=3

// Coarse bucketing for CSR build: 64 nodes per bucket
#define CB 1563              // ceil(NN/64)
#define CBP 1568             // padded bucket count (multiple of 32)
#define EPB 4096             // edges per block in pass A
#define A1B 391              // ceil(NE/EPB)

typedef unsigned short u16;
using short8 = __attribute__((ext_vector_type(8))) short;  // 8 bf16 (4 VGPRs)
using f32x4  = __attribute__((ext_vector_type(4))) float;  // MFMA accum

// bf16 helpers (round-to-nearest-even via bit trick)
__device__ inline u16 f2bf(float f) {
    unsigned u = __float_as_uint(f);
    unsigned r = u + 0x7fffu + ((u >> 16) & 1u);
    return (u16)(r >> 16);
}
__device__ inline float bflo(unsigned u) { return __uint_as_float(u << 16); }
__device__ inline float bfhi(unsigned u) { return __uint_as_float(u & 0xffff0000u); }

// 4-byte edge record: [31:17] = bf16 weight sans sign (w >= 0), [16:0] = src
__device__ inline float ew_of(unsigned p) { return __uint_as_float((p >> 17) << 16); }
__device__ inline int   src_of(unsigned p) { return (int)(p & 0x1FFFFu); }

// ---------------------------------------------------------------------------
// Graph preprocessing: atomic-free two-level bucket CSR build.
// ---------------------------------------------------------------------------

// A1: per-block histogram of coarse buckets -> M[blk][CBP]
__global__ __launch_bounds__(256) void hist_k(const int* __restrict__ col,
                                              unsigned* __restrict__ M) {
    __shared__ unsigned h[CBP];
    for (int i = threadIdx.x; i < CBP; i += 256) h[i] = 0;
    __syncthreads();
    int base = blockIdx.x * EPB;
    for (int i = threadIdx.x; i < EPB; i += 256) {
        int e = base + i;
        if (e < NE) atomicAdd(&h[col[e] >> 6], 1u);
    }
    __syncthreads();
    unsigned* mrow = M + (size_t)blockIdx.x * CBP;
    for (int i = threadIdx.x; i < CBP; i += 256) mrow[i] = h[i];
}

// A2a: column totals of M -> tot[CBP]
__global__ __launch_bounds__(256) void totals_k(const unsigned* __restrict__ M,
                                                unsigned* __restrict__ tot) {
    int b = blockIdx.x * 256 + threadIdx.x;
    if (b >= CBP) return;
    unsigned s = 0;
    for (int r = 0; r < A1B; ++r) s += M[(size_t)r * CBP + b];
    tot[b] = s;
}

// A2b: exclusive scan of tot -> cb[0..CBP]  (single block)
__global__ __launch_bounds__(256) void scanb_k(const unsigned* __restrict__ tot,
                                               unsigned* __restrict__ cb) {
    __shared__ unsigned part[256];
    int t = threadIdx.x;
    unsigned loc[7];
    unsigned s = 0;
#pragma unroll
    for (int k = 0; k < 7; ++k) {
        int i = t * 7 + k;
        unsigned v = (i < CBP) ? tot[i] : 0;
        loc[k] = s; s += v;
    }
    part[t] = s;
    __syncthreads();
    for (int off = 1; off < 256; off <<= 1) {
        unsigned x = (t >= off) ? part[t - off] : 0;
        __syncthreads();
        part[t] += x;
        __syncthreads();
    }
    unsigned base = (t > 0) ? part[t - 1] : 0;
#pragma unroll
    for (int k = 0; k < 7; ++k) {
        int i = t * 7 + k;
        if (i <= CBP) cb[i] = base + loc[k];
    }
}

// A2c: rewrite M in place to per-(blk,bucket) base
__global__ __launch_bounds__(256) void base_k(const unsigned* __restrict__ cb,
                                              unsigned* __restrict__ M) {
    int b = blockIdx.x * 256 + threadIdx.x;
    if (b >= CBP) return;
    unsigned run = cb[b];
    for (int r = 0; r < A1B; ++r) {
        unsigned v = M[(size_t)r * CBP + b];
        M[(size_t)r * CBP + b] = run;
        run += v;
    }
}

// A3: partition edges into bucket segments (packed: src | colLow<<17, w)
__global__ __launch_bounds__(256) void part_k(const int* __restrict__ row,
                                              const int* __restrict__ col,
                                              const float* __restrict__ ew,
                                              const unsigned* __restrict__ M,
                                              int2* __restrict__ Abuf) {
    __shared__ unsigned cur[CBP];
    const unsigned* mrow = M + (size_t)blockIdx.x * CBP;
    for (int i = threadIdx.x; i < CBP; i += 256) cur[i] = mrow[i];
    __syncthreads();
    int base = blockIdx.x * EPB;
    for (int i = threadIdx.x; i < EPB; i += 256) {
        int e = base + i;
        if (e < NE) {
            int c = col[e];
            unsigned pos = atomicAdd(&cur[c >> 6], 1u);
            Abuf[pos] = make_int2(row[e] | ((c & 63) << 17), __float_as_int(ew[e]));
        }
    }
}

// B: per-bucket LDS counting sort -> epair + rowptr; fused deg/dis.
__global__ __launch_bounds__(256) void build_k(const int2* __restrict__ Abuf,
                                               const unsigned* __restrict__ cb,
                                               int* __restrict__ rowptr,
                                               int2* __restrict__ epair,
                                               float* __restrict__ dis) {
    int b = blockIdx.x;     // 0..CB-1
    int t = threadIdx.x;
    __shared__ int cnt[64];
    __shared__ int offs[64];
    __shared__ int ex[64];
    __shared__ float dsum[64];
    if (t < 64) { cnt[t] = 0; dsum[t] = 0.f; }
    __syncthreads();
    unsigned s = cb[b], e = cb[b + 1];
    int n = (int)(e - s);
    // pass 1: count + weighted degree
    for (int i = t; i < n; i += 256) {
        int2 p = Abuf[s + i];
        int cl = (p.x >> 17) & 63;
        atomicAdd(&cnt[cl], 1);
        atomicAdd(&dsum[cl], __int_as_float(p.y));
    }
    __syncthreads();
    // exclusive scan of cnt[64]
    if (t < 64) offs[t] = cnt[t];
    __syncthreads();
    for (int off = 1; off < 64; off <<= 1) {
        int x = 0;
        if (t < 64 && t >= off) x = offs[t - off];
        __syncthreads();
        if (t < 64) offs[t] += x;
        __syncthreads();
    }
    if (t < 64) { ex[t] = offs[t] - cnt[t]; cnt[t] = 0; }
    __syncthreads();
    // pass 2: scatter into sorted positions (2nd read hits L2)
    for (int i = t; i < n; i += 256) {
        int2 p = Abuf[s + i];
        int cl = (p.x >> 17) & 63;
        int r = atomicAdd(&cnt[cl], 1);
        epair[s + ex[cl] + r] = make_int2(p.x & 0x1FFFF, p.y);
    }
    // rowptr + dis
    if (t < 64) {
        int v = b * 64 + t;
        if (v < NN) {
            rowptr[v] = (int)s + ex[t];
            float d = dsum[t];
            dis[v] = (d > 0.f) ? (1.0f / sqrtf(d)) : 0.f;
        }
    }
    if (b == CB - 1 && t == 0) rowptr[NN] = NE;
}

// norm + compress: epc[i] = (bf16bits(dis[src]*w*dis[v]) & 0x7FFF)<<17 | src
__global__ void norm_k(const int* __restrict__ rowptr, const float* __restrict__ dis,
                       const int2* __restrict__ epair, unsigned* __restrict__ epc) {
    int v = blockIdx.x * 256 + threadIdx.x;
    if (v >= NN) return;
    float dv = dis[v];
    int s = rowptr[v], e = rowptr[v + 1];
    for (int i = s; i < e; ++i) {
        int2 p = epair[i];
        float w = dis[p.x] * __int_as_float(p.y) * dv;
        unsigned wb = (unsigned)f2bf(w) & 0x7FFFu;
        epc[i] = (wb << 17) | (unsigned)p.x;
    }
}

// ---------------------------------------------------------------------------
// Weight prep (single launch): Wt[j][k] = bf16(W[k][j])
// ranges: [0, 8192) -> W0 (K=64); [8192, 73728) -> W1; [73728, 139264) -> W2
// ---------------------------------------------------------------------------
__global__ void wtall_k(const float* __restrict__ W0, u16* __restrict__ Wt0,
                        const float* __restrict__ W1, u16* __restrict__ Wt1,
                        const float* __restrict__ W2, u16* __restrict__ Wt2) {
    int id = blockIdx.x * 256 + threadIdx.x;
    const int N0 = 128 * 64, N1 = 128 * 512;
    if (id < N0) {
        int j = id / 64, k = id % 64;
        Wt0[(size_t)j * 64 + k] = f2bf(W0[(size_t)k * 128 + j]);
    } else if (id < N0 + N1) {
        int t = id - N0;
        int j = t / 512, k = t % 512;
        Wt1[(size_t)j * 512 + k] = f2bf(W1[(size_t)k * 128 + j]);
    } else if (id < N0 + 2 * N1) {
        int t = id - N0 - N1;
        int j = t / 512, k = t % 512;
        Wt2[(size_t)j * 512 + k] = f2bf(W2[(size_t)k * 128 + j]);
    }
}

// ---------------------------------------------------------------------------
// Propagation
// ---------------------------------------------------------------------------

// 16-wide fp32 features (layer-0 hops): 4 lanes per node, float4 each.
__global__ void prop16_k(const float* __restrict__ hin, float* __restrict__ hout,
                         const int* __restrict__ rowptr, const unsigned* __restrict__ epc) {
    int t = blockIdx.x * 256 + threadIdx.x;
    int v = t >> 2, q = t & 3;
    if (v >= NN) return;
    int s = rowptr[v], e = rowptr[v + 1];
    const float* __restrict__ hq = hin + q * 4;
    float4 a0 = make_float4(0.f, 0.f, 0.f, 0.f);
    float4 a1 = make_float4(0.f, 0.f, 0.f, 0.f);
    int i = s;
    for (; i + 3 < e; i += 4) {
        unsigned p0 = epc[i], p1 = epc[i + 1], p2 = epc[i + 2], p3 = epc[i + 3];
        float4 h0 = *reinterpret_cast<const float4*>(hq + (size_t)src_of(p0) * 16);
        float4 h1 = *reinterpret_cast<const float4*>(hq + (size_t)src_of(p1) * 16);
        float4 h2 = *reinterpret_cast<const float4*>(hq + (size_t)src_of(p2) * 16);
        float4 h3 = *reinterpret_cast<const float4*>(hq + (size_t)src_of(p3) * 16);
        float w0 = ew_of(p0), w1 = ew_of(p1), w2 = ew_of(p2), w3 = ew_of(p3);
        a0.x += w0 * h0.x; a0.y += w0 * h0.y; a0.z += w0 * h0.z; a0.w += w0 * h0.w;
        a1.x += w1 * h1.x; a1.y += w1 * h1.y; a1.z += w1 * h1.z; a1.w += w1 * h1.w;
        a0.x += w2 * h2.x; a0.y += w2 * h2.y; a0.z += w2 * h2.z; a0.w += w2 * h2.w;
        a1.x += w3 * h3.x; a1.y += w3 * h3.y; a1.z += w3 * h3.z; a1.w += w3 * h3.w;
    }
    for (; i < e; ++i) {
        unsigned p = epc[i];
        float w = ew_of(p);
        float4 h = *reinterpret_cast<const float4*>(hq + (size_t)src_of(p) * 16);
        a0.x += w * h.x; a0.y += w * h.y; a0.z += w * h.z; a0.w += w * h.w;
    }
    float4 acc = make_float4(a0.x + a1.x, a0.y + a1.y, a0.z + a1.z, a0.w + a1.w);
    *reinterpret_cast<float4*>(hout + (size_t)v * 16 + q * 4) = acc;
}

// Pack x,P1,P2,P3 (fp32 [NN][16] each) -> Xcat bf16 [NN][64]
__global__ void pack_k(const float* __restrict__ x, const float* __restrict__ p1,
                       const float* __restrict__ p2, const float* __restrict__ p3,
                       u16* __restrict__ Xcat) {
    int id = blockIdx.x * 256 + threadIdx.x;
    if (id >= NN * 4) return;
    int v = id >> 2, s = id & 3;
    const float* src = (s == 0 ? x : s == 1 ? p1 : s == 2 ? p2 : p3) + (size_t)v * 16;
    unsigned* dst = (unsigned*)(Xcat + (size_t)v * 64 + s * 16);
#pragma unroll
    for (int f = 0; f < 8; ++f) {
        dst[f] = (unsigned)f2bf(src[2 * f]) | ((unsigned)f2bf(src[2 * f + 1]) << 16);
    }
}

// 128-wide bf16 prop: ONE wave per node; 16 lanes serve one edge with
// dwordx4 (16B = 8 features per lane) -> 4 edges per wave-load, unroll x2.
// At the L2-miss service ceiling for this random-gather pattern (R5/R6/R7/R10).
__global__ __launch_bounds__(256) void propbf_k(
    const u16* __restrict__ hin, u16* __restrict__ hout,
    const int* __restrict__ rowptr, const unsigned* __restrict__ epc) {
    int wid = (blockIdx.x * 256 + threadIdx.x) >> 6;   // grid = NN*64/256
    int lane = threadIdx.x & 63;
    int g = lane >> 4;          // edge group 0..3
    int l = lane & 15;          // feature slot: features [8l, 8l+8)
    int v = __builtin_amdgcn_readfirstlane(wid);
    int s = rowptr[v], e = rowptr[v + 1];
    const u16* __restrict__ hb = hin + l * 8;
    float a[8];
#pragma unroll
    for (int k = 0; k < 8; ++k) a[k] = 0.f;

    int i = s;
    for (; i + 7 < e; i += 8) {
        unsigned pa = epc[i + g];
        unsigned pb = epc[i + 4 + g];
        uint4 ha = *(const uint4*)(hb + (size_t)src_of(pa) * 512);
        uint4 hc = *(const uint4*)(hb + (size_t)src_of(pb) * 512);
        float wa = ew_of(pa), wb = ew_of(pb);
        a[0] += wa * bflo(ha.x); a[1] += wa * bfhi(ha.x);
        a[2] += wa * bflo(ha.y); a[3] += wa * bfhi(ha.y);
        a[4] += wa * bflo(ha.z); a[5] += wa * bfhi(ha.z);
        a[6] += wa * bflo(ha.w); a[7] += wa * bfhi(ha.w);
        a[0] += wb * bflo(hc.x); a[1] += wb * bfhi(hc.x);
        a[2] += wb * bflo(hc.y); a[3] += wb * bfhi(hc.y);
        a[4] += wb * bflo(hc.z); a[5] += wb * bfhi(hc.z);
        a[6] += wb * bflo(hc.w); a[7] += wb * bfhi(hc.w);
    }
    for (; i < e; i += 4) {
        int idx = i + g;
        unsigned p = (idx < e) ? epc[idx] : 0u;
        uint4 h = *(const uint4*)(hb + (size_t)src_of(p) * 512);
        float w = ew_of(p);
        a[0] += w * bflo(h.x); a[1] += w * bfhi(h.x);
        a[2] += w * bflo(h.y); a[3] += w * bfhi(h.y);
        a[4] += w * bflo(h.z); a[5] += w * bfhi(h.z);
        a[6] += w * bflo(h.w); a[7] += w * bfhi(h.w);
    }
#pragma unroll
    for (int k = 0; k < 8; ++k) {
        a[k] += __shfl_xor(a[k], 16);
        a[k] += __shfl_xor(a[k], 32);
    }
    if (g == 0) {
        uint4 o;
        o.x = (unsigned)f2bf(a[0]) | ((unsigned)f2bf(a[1]) << 16);
        o.y = (unsigned)f2bf(a[2]) | ((unsigned)f2bf(a[3]) << 16);
        o.z = (unsigned)f2bf(a[4]) | ((unsigned)f2bf(a[5]) << 16);
        o.w = (unsigned)f2bf(a[6]) | ((unsigned)f2bf(a[7]) << 16);
        *(uint4*)(hout + (size_t)v * 512 + l * 8) = o;
    }
}

// ---------------------------------------------------------------------------
// MFMA GEMM v4: C[NN][128] = A[NN][K]bf16 @ W[K][128] (+bias, relu) -> bf16,
// out stride 512. B staged in 16KB K-chunks (128 rows x 64 k), DOUBLE-
// BUFFERED (32KB LDS) -> occupancy VGPR-bound instead of LDS-bound 8 (R9
// lesson). One 256-row tile per block (grid=391): write locality (R8 lesson)
// + perfect balance. T14 split staging: issue loads for chunk c+1 ->
// compute chunk c -> ds_write -> barrier.
// ---------------------------------------------------------------------------
template <int K, int RELU>
__global__ __launch_bounds__(512) void mgemm3_k(
    const u16* __restrict__ A, const u16* __restrict__ Bt,
    const float* __restrict__ bias, u16* __restrict__ outb) {
    const int NCH = K / 64;               // 16KB chunks
    __shared__ u16 smB[2][64 * 128];
    int tid = threadIdx.x;
    int lane = tid & 63;
    int wv = tid >> 6;
    int r = lane & 15, h = lane >> 4;

    int v0 = blockIdx.x * 256 + wv * 32;
    bool active = v0 < NN;
    int arow0 = active ? v0 : 0;
    const u16* a0p = A + (size_t)(arow0 + r) * K + h * 8;
    const u16* a1p = a0p + (size_t)16 * K;

    float bj[8];
#pragma unroll
    for (int j = 0; j < 8; ++j) bj[j] = bias[j * 16 + r];

    // staging addresses (chunk image byte d; LDS[d] = IMG[d ^ swz(row)])
    int da = wv * 1024 + lane * 16;
    int db = da + 8192;
    int rowa = da >> 7, rowb = db >> 7;
    int sa = (da ^ ((rowa & 7) << 4)) & 127;
    int sb = (db ^ ((rowb & 7) << 4)) & 127;
    const char* gA = (const char*)Bt + (size_t)rowa * (2 * K) + sa;
    const char* gB = (const char*)Bt + (size_t)rowb * (2 * K) + sb;

    // prologue: stage chunk 0 into buf 0
    short8 ga = *(const short8*)(gA);
    short8 gb = *(const short8*)(gB);
    *(short8*)((char*)smB[0] + da) = ga;
    *(short8*)((char*)smB[0] + db) = gb;
    __syncthreads();

    f32x4 acc0[8], acc1[8];
#pragma unroll
    for (int j = 0; j < 8; ++j) {
        acc0[j] = {0.f, 0.f, 0.f, 0.f};
        acc1[j] = {0.f, 0.f, 0.f, 0.f};
    }

    int buf = 0;
    for (int c = 0; c < NCH; ++c) {
        // issue loads for next chunk (hide under compute)
        if (c + 1 < NCH) {
            ga = *(const short8*)(gA + (c + 1) * 128);
            gb = *(const short8*)(gB + (c + 1) * 128);
        }
        const char* bbase = (const char*)smB[buf];
#pragma unroll
        for (int kk = 0; kk < 2; ++kk) {
            short8 a0 = *(const short8*)(a0p + c * 64 + kk * 32);
            short8 a1 = *(const short8*)(a1p + c * 64 + kk * 32);
#pragma unroll
            for (int j = 0; j < 8; ++j) {
                int bb = ((j * 16 + r) * 128 + kk * 64 + h * 16) ^ ((r & 7) << 4);
                short8 b = *(const short8*)(bbase + bb);
                acc0[j] = __builtin_amdgcn_mfma_f32_16x16x32_bf16(a0, b, acc0[j], 0, 0, 0);
                acc1[j] = __builtin_amdgcn_mfma_f32_16x16x32_bf16(a1, b, acc1[j], 0, 0, 0);
            }
        }
        if (c + 1 < NCH) {
            *(short8*)((char*)smB[buf ^ 1] + da) = ga;
            *(short8*)((char*)smB[buf ^ 1] + db) = gb;
        }
        __syncthreads();
        buf ^= 1;
    }

    if (active) {
        // Epilogue: i-outer, j-inner so 32B half-line stores are adjacent.
#pragma unroll
        for (int i = 0; i < 4; ++i) {
            int row0 = v0 + h * 4 + i;
#pragma unroll
            for (int j = 0; j < 8; ++j) {
                float c0 = acc0[j][i] + bj[j];
                float c1 = acc1[j][i] + bj[j];
                if (RELU) { c0 = fmaxf(c0, 0.f); c1 = fmaxf(c1, 0.f); }
                outb[(size_t)row0 * 512 + j * 16 + r] = f2bf(c0);
                outb[(size_t)(row0 + 16) * 512 + j * 16 + r] = f2bf(c1);
            }
        }
    }
}

// Final fc: out[v][0..3] = bfc + h[v][:] @ Wfc[128][4]; h bf16 stride 512.
__global__ void fcb_k(const u16* __restrict__ H, const float* __restrict__ Wfc,
                      const float* __restrict__ bfc, float* __restrict__ out) {
    int t = blockIdx.x * 256 + threadIdx.x;   // grid = NN*64/256
    int v = t >> 6, p = t & 63;
    unsigned u = *(const unsigned*)(H + (size_t)v * 512 + p * 2);
    float h0 = bflo(u), h1 = bfhi(u);
    float4 w0 = reinterpret_cast<const float4*>(Wfc)[2 * p];
    float4 w1 = reinterpret_cast<const float4*>(Wfc)[2 * p + 1];
    float s0 = h0 * w0.x + h1 * w1.x;
    float s1 = h0 * w0.y + h1 * w1.y;
    float s2 = h0 * w0.z + h1 * w1.z;
    float s3 = h0 * w0.w + h1 * w1.w;
#pragma unroll
    for (int off = 32; off; off >>= 1) {
        s0 += __shfl_xor(s0, off);
        s1 += __shfl_xor(s1, off);
        s2 += __shfl_xor(s2, off);
        s3 += __shfl_xor(s3, off);
    }
    if (p == 0) {
        float4 o = make_float4(s0 + bfc[0], s1 + bfc[1], s2 + bfc[2], s3 + bfc[3]);
        reinterpret_cast<float4*>(out)[v] = o;
    }
}

// ---------------------------------------------------------------------------

extern "C" void kernel_launch(void* const* d_in, const int* in_sizes, int n_in,
                              void* d_out, int out_size, void* d_ws, size_t ws_size,
                              hipStream_t stream) {
    const float* x    = (const float*)d_in[0];
    const int*   ei   = (const int*)d_in[1];      // [2][E] int32
    const float* ea   = (const float*)d_in[2];    // [E]
    const float* W0   = (const float*)d_in[3];    // [4][16][128] = [64][128]
    const float* b0   = (const float*)d_in[4];
    const float* W1   = (const float*)d_in[5];    // [4][128][128] = [512][128]
    const float* b1   = (const float*)d_in[6];
    const float* W2   = (const float*)d_in[7];
    const float* b2   = (const float*)d_in[8];
    const float* Wfc  = (const float*)d_in[9];    // [128][4]
    const float* bfc  = (const float*)d_in[10];
    float* out = (float*)d_out;

    const int* row = ei;
    const int* col = ei + NE;

    // ws layout (256B aligned chunks)
    char* w = (char*)d_ws;
    size_t off = 0;
    auto alloc = [&](size_t bytes) {
        size_t o = off;
        off += (bytes + 255) & ~(size_t)255;
        return (void*)(w + o);
    };
    int*      rowptr = (int*)     alloc((size_t)(NN + 1) * 4);
    float*    dis    = (float*)   alloc((size_t)NN * 4);
    unsigned* M      = (unsigned*)alloc((size_t)A1B * CBP * 4);  // 2.45 MB
    unsigned* tot    = (unsigned*)alloc((size_t)CBP * 4);
    unsigned* cb     = (unsigned*)alloc((size_t)(CBP + 1) * 4);
    int2*     Abuf   = (int2*)    alloc((size_t)NE * 8);         // 12.8 MB
    int2*     epair  = (int2*)    alloc((size_t)NE * 8);         // 12.8 MB
    unsigned* epc    = (unsigned*)alloc((size_t)NE * 4);         // 6.4 MB
    u16*      Wt0    = (u16*)     alloc((size_t)128 * 64 * 2);
    u16*      Wt1    = (u16*)     alloc((size_t)128 * 512 * 2);
    u16*      Wt2    = (u16*)     alloc((size_t)128 * 512 * 2);
    char*     ureg   = (char*)    alloc((size_t)NN * 128 * 4);   // 51.2 MB
    float* P1   = (float*)(ureg);
    float* P2   = (float*)(ureg + (size_t)NN * 16 * 4);
    float* P3   = (float*)(ureg + (size_t)NN * 32 * 4);
    u16*   Xcat = (u16*)  (ureg + (size_t)NN * 48 * 4);
    u16*      Hcat   = (u16*)     alloc((size_t)NN * 512 * 2);   // 102.4 MB
    (void)ws_size;

    const int nScanB = (NN + 255) / 256;  // 391
    const int nPropB = NN * 64 / 256;     // 25000 (one wave per node)
    const int nTiles = (NN + 255) / 256;  // 391 row-tiles of 256
    const int nBkt   = (CBP + 255) / 256; // 7

    // CSR build (atomic-free, streaming; no global memset needed)
    hist_k  <<<A1B,  256, 0, stream>>>(col, M);
    totals_k<<<nBkt, 256, 0, stream>>>(M, tot);
    scanb_k <<<1,    256, 0, stream>>>(tot, cb);
    base_k  <<<nBkt, 256, 0, stream>>>(cb, M);
    part_k  <<<A1B,  256, 0, stream>>>(row, col, ea, M, Abuf);
    build_k <<<CB,   256, 0, stream>>>(Abuf, cb, rowptr, epair, dis);
    norm_k  <<<nScanB, 256, 0, stream>>>(rowptr, dis, epair, epc);

    // Weight transposes (bf16), single launch
    wtall_k<<<(128 * 64 + 2 * 128 * 512 + 255) / 256, 256, 0, stream>>>(
        W0, Wt0, W1, Wt1, W2, Wt2);

    // Layer 0: fp32 16-wide hops, pack to bf16, MFMA K=64 -> Hcat slice0
    const int n16B = (NN * 4 + 255) / 256;
    prop16_k<<<n16B, 256, 0, stream>>>(x,  P1, rowptr, epc);
    prop16_k<<<n16B, 256, 0, stream>>>(P1, P2, rowptr, epc);
    prop16_k<<<n16B, 256, 0, stream>>>(P2, P3, rowptr, epc);
    pack_k<<<n16B, 256, 0, stream>>>(x, P1, P2, P3, Xcat);
    mgemm3_k<64, 1><<<nTiles, 512, 0, stream>>>(Xcat, Wt0, b0, Hcat);

    // Layer 1: hops fill slices 1..3, fused GEMM K=512 -> slice0 (in place)
    propbf_k<<<nPropB, 256, 0, stream>>>(Hcat,       Hcat + 128, rowptr, epc);
    propbf_k<<<nPropB, 256, 0, stream>>>(Hcat + 128, Hcat + 256, rowptr, epc);
    propbf_k<<<nPropB, 256, 0, stream>>>(Hcat + 256, Hcat + 384, rowptr, epc);
    mgemm3_k<512, 1><<<nTiles, 512, 0, stream>>>(Hcat, Wt1, b1, Hcat);

    // Layer 2: same, final GEMM -> slice0 bf16 (no relu)
    propbf_k<<<nPropB, 256, 0, stream>>>(Hcat,       Hcat + 128, rowptr, epc);
    propbf_k<<<nPropB, 256, 0, stream>>>(Hcat + 128, Hcat + 256, rowptr, epc);
    propbf_k<<<nPropB, 256, 0, stream>>>(Hcat + 256, Hcat + 384, rowptr, epc);
    mgemm3_k<512, 0><<<nTiles, 512, 0, stream>>>(Hcat, Wt2, b2, Hcat);

    // Final projection (reads bf16 slice0)
    fcb_k<<<nPropB, 256, 0, stream>>>(Hcat, Wfc, bfc, out);
}